// Round 1
// baseline (332.853 us; speedup 1.0000x reference)
//
#include <hip/hip_runtime.h>
#include <hip/hip_bf16.h>
#include <stdint.h>

typedef __hip_bfloat16 bf16;

#define VOCABN 100000
#define EDIM 128
#define BN 16
#define SN 2048

// ws float offsets
#define H_OFF    0         // h (2048 floats); reused as u1 after k_heads
#define U_OFF    2048
#define L0_OFF   4096      // 32768 floats (row buffer: l0, then l1 in place)
#define DUP_OFF  36864     // 16*16*128 = 32768 floats (partial du)
#define PBV_OFF  69648     // 1200
#define PBI_OFF  70848     // 1200
#define G_OFF    73728     // uint32 region: 2 tables * 16*2048*64 = 4194304 u32 (16 MB)

// ---------- threefry2x32 (JAX partitionable) ----------
__host__ __device__ inline void tf2x32(uint32_t k0, uint32_t k1,
                                       uint32_t x0, uint32_t x1,
                                       uint32_t* o0, uint32_t* o1) {
  const uint32_t rotA[4] = {13u, 15u, 26u, 6u};
  const uint32_t rotB[4] = {17u, 29u, 16u, 24u};
  uint32_t ks0 = k0, ks1 = k1, ks2 = k0 ^ k1 ^ 0x1BD11BDAu;
  x0 += ks0; x1 += ks1;
#pragma unroll
  for (int g = 0; g < 5; ++g) {
    const uint32_t* r = (g & 1) ? rotB : rotA;
#pragma unroll
    for (int i = 0; i < 4; ++i) {
      x0 += x1;
      x1 = (x1 << r[i]) | (x1 >> (32u - r[i]));
      x1 ^= x0;
    }
    uint32_t a0 = (g % 3 == 0) ? ks1 : ((g % 3 == 1) ? ks2 : ks0);
    uint32_t a1 = (g % 3 == 0) ? ks2 : ((g % 3 == 1) ? ks0 : ks1);
    x0 += a0;
    x1 += a1 + (uint32_t)(g + 1);
  }
  *o0 = x0; *o1 = x1;
}

__device__ inline float blo(uint32_t v) { return __uint_as_float(v << 16); }
__device__ inline float bhi(uint32_t v) { return __uint_as_float(v & 0xffff0000u); }
__device__ inline uint16_t f2bu(float f) {
  bf16 h = __float2bfloat16(f);
  uint16_t u; __builtin_memcpy(&u, &h, 2); return u;
}
__device__ inline float gumbel(uint32_t ka, uint32_t kb, uint32_t flat) {
  uint32_t o0, o1;
  tf2x32(ka, kb, 0u, flat, &o0, &o1);
  uint32_t bits = o0 ^ o1;
  float u0 = __uint_as_float((bits >> 9) | 0x3f800000u) - 1.0f;
  float uu = fmaxf(1e-10f, u0 + 1e-10f);
  return -logf(-logf(uu));
}

// ---------- h = hidden @ Wm^T + Wb ; u = h ----------
__global__ void k_h(const float* __restrict__ hidden, const float* __restrict__ Wm,
                    const float* __restrict__ Wb, float* __restrict__ h,
                    float* __restrict__ u) {
  int b = blockIdx.x, j = threadIdx.x;
  const float4* wr = (const float4*)(Wm + (size_t)j * EDIM);
  const float4* hr = (const float4*)(hidden + (size_t)b * EDIM);
  float acc = Wb[j];
#pragma unroll
  for (int i = 0; i < 32; ++i) {
    float4 w4 = wr[i], h4 = hr[i];
    acc += w4.x * h4.x + w4.y * h4.y + w4.z * h4.z + w4.w * h4.w;
  }
  h[b * EDIM + j] = acc;
  u[b * EDIM + j] = acc;
}

// ---------- heads: logits to out; per-chunk gumbel-argmax partials to pbv/pbi ----------
__global__ void k_heads(const float* __restrict__ h,
                        const float* __restrict__ W1w, const float* __restrict__ W1b,
                        const float* __restrict__ W3w, const float* __restrict__ W3b,
                        const float* __restrict__ W4w, const float* __restrict__ W4b,
                        float* __restrict__ out, float* __restrict__ pbv,
                        int* __restrict__ pbi,
                        uint32_t k0a, uint32_t k0b, uint32_t k1a, uint32_t k1b,
                        uint32_t k2a, uint32_t k2b) {
  int bid = blockIdx.x, tid = threadIdx.x;
  __shared__ float hb[EDIM];
  __shared__ float sv[256];
  __shared__ int si[256];
  int head, b2, base, cnt, chunk, N;
  const float *W, *bias; size_t lg_off; uint32_t ka, kb;
  if (bid < 400)      { head = 1; b2 = bid / 25; chunk = bid % 25; base = chunk * 160; cnt = 160;
                        W = W3w; bias = W3b; N = 4000; lg_off = 64;     ka = k1a; kb = k1b; }
  else if (bid < 416) { head = 2; b2 = bid - 400; chunk = 0; base = 0; cnt = 200;
                        W = W4w; bias = W4b; N = 200;  lg_off = 128064; ka = k2a; kb = k2b; }
  else                { head = 0; b2 = bid - 416; chunk = 0; base = 0; cnt = 2;
                        W = W1w; bias = W1b; N = 2;    lg_off = 0;      ka = k0a; kb = k0b; }
  if (tid < 128) hb[tid] = h[b2 * EDIM + tid];
  __syncthreads();
  float best = -INFINITY; int bi = 0x7FFFFFFF;
  if (tid < cnt) {
    int c = base + tid;
    const float4* wr = (const float4*)(W + (size_t)c * EDIM);
    const float4* hb4 = (const float4*)hb;
    float acc = bias[c];
#pragma unroll
    for (int i = 0; i < 32; ++i) {
      float4 w4 = wr[i], h4 = hb4[i];
      acc += w4.x * h4.x + w4.y * h4.y + w4.z * h4.z + w4.w * h4.w;
    }
    out[lg_off + (size_t)b2 * N + c] = acc;
    best = acc + gumbel(ka, kb, (uint32_t)(b2 * N + c));
    bi = c;
  }
  sv[tid] = best; si[tid] = bi;
  __syncthreads();
  for (int s2 = 128; s2 > 0; s2 >>= 1) {
    if (tid < s2) {
      float ov = sv[tid + s2]; int oi = si[tid + s2];
      if (ov > sv[tid] || (ov == sv[tid] && oi < si[tid])) { sv[tid] = ov; si[tid] = oi; }
    }
    __syncthreads();
  }
  if (tid == 0) {
    pbv[(head * 16 + b2) * 25 + chunk] = sv[0];
    pbi[(head * 16 + b2) * 25 + chunk] = si[0];
  }
}

// ---------- one-hots: each thread re-scans its (head,b)'s chunk partials ----------
__global__ void k_onehot(const float* __restrict__ pbv, const int* __restrict__ pbi,
                         float* __restrict__ out) {
  int g = blockIdx.x * 256 + threadIdx.x;
  if (g >= 67232) return;
  int head, b2, c; size_t off; int nch;
  if (g < 64000)      { head = 1; b2 = g / 4000; c = g % 4000; off = 64064 + g;          nch = 25; }
  else if (g < 67200) { int gg = g - 64000; head = 2; b2 = gg / 200; c = gg % 200; off = 131264 + gg; nch = 1; }
  else                { int gg = g - 67200; head = 0; b2 = gg >> 1; c = gg & 1;   off = 32 + gg;     nch = 1; }
  float bv = -INFINITY; int bi = 0x7FFFFFFF;
  for (int ch = 0; ch < nch; ++ch) {
    float v = pbv[(head * 16 + b2) * 25 + ch];
    int i2 = pbi[(head * 16 + b2) * 25 + ch];
    if (v > bv || (v == bv && i2 < bi)) { bv = v; bi = i2; }
  }
  out[off] = (c == bi) ? 1.0f : 0.0f;
}

// ---------- gather: t=0 -> l0 directly (f32 dot with u); t=1,2 -> bf16 G ----------
__global__ void k_gather_l0(const int* __restrict__ story, const float* __restrict__ C,
                            const float* __restrict__ u, uint32_t* __restrict__ G,
                            float* __restrict__ l0) {
  int wid = (blockIdx.x << 2) | (threadIdx.x >> 6);  // 0..98303
  int lane = threadIdx.x & 63;
  int t = wid >> 15;
  int bs = wid & 32767;
  int4 idx = ((const int4*)story)[bs];
  const float2* r0 = (const float2*)(C + ((size_t)t * VOCABN + idx.x) * EDIM);
  const float2* r1 = (const float2*)(C + ((size_t)t * VOCABN + idx.y) * EDIM);
  const float2* r2 = (const float2*)(C + ((size_t)t * VOCABN + idx.z) * EDIM);
  const float2* r3 = (const float2*)(C + ((size_t)t * VOCABN + idx.w) * EDIM);
  float2 a = r0[lane], b = r1[lane], c = r2[lane], d = r3[lane];
  float lo = a.x + b.x + c.x + d.x;
  float hi = a.y + b.y + c.y + d.y;
  if (t == 0) {
    float2 uu = ((const float2*)(u + ((bs >> 11) << 7)))[lane];
    float s = lo * uu.x + hi * uu.y;
#pragma unroll
    for (int off = 32; off > 0; off >>= 1) s += __shfl_xor(s, off, 64);
    if (lane == 0) l0[bs] = s;
  } else {
    G[((size_t)(t - 1) * BN * SN + bs) * 64 + lane] =
        (uint32_t)f2bu(lo) | ((uint32_t)f2bu(hi) << 16);
  }
}

// ---------- hop phase B: per-slice softmax-weighted partial du ----------
// grid = BN*16 blocks, 256 threads. Each block: full-row softmax stats
// (redundant, cheap) + partial du over its 128-cell slice of Gt, scaled
// by invS, written to dup[b][k][128].
__global__ void __launch_bounds__(256) k_hopB(const uint32_t* __restrict__ Gt,
                                              const float* __restrict__ row_in,
                                              float* __restrict__ dup) {
  const int b = blockIdx.x >> 4, k = blockIdx.x & 15;
  const int tid = threadIdx.x, wave = tid >> 6, lane = tid & 63;
  __shared__ float sr[SN];
  __shared__ float red[4];
  __shared__ float acc[4][EDIM];

  const float4* rin = (const float4*)(row_in + (size_t)b * SN);
  float4* sr4 = (float4*)sr;
  for (int i = tid; i < SN / 4; i += 256) sr4[i] = rin[i];
  __syncthreads();

  // row max
  float m = -INFINITY;
  for (int i = tid; i < SN; i += 256) m = fmaxf(m, sr[i]);
#pragma unroll
  for (int off = 32; off > 0; off >>= 1) m = fmaxf(m, __shfl_xor(m, off, 64));
  if (lane == 0) red[wave] = m;
  __syncthreads();
  m = fmaxf(fmaxf(red[0], red[1]), fmaxf(red[2], red[3]));

  // row sum of exp
  float s = 0.f;
  for (int i = tid; i < SN; i += 256) s += expf(sr[i] - m);
#pragma unroll
  for (int off = 32; off > 0; off >>= 1) s += __shfl_xor(s, off, 64);
  __syncthreads();                 // red reads above done before overwrite
  if (lane == 0) red[wave] = s;
  __syncthreads();
  float invS = 1.0f / (red[0] + red[1] + red[2] + red[3]);

  // partial du over cells [k*128, k*128+128): wave covers 32, 4 cells at a time
  const uint32_t* Gb = Gt + (size_t)b * SN * 64;
  int sub = lane >> 4, le = lane & 15;
  float a[8] = {0, 0, 0, 0, 0, 0, 0, 0};
#pragma unroll
  for (int it = 0; it < 8; ++it) {
    int cell = k * 128 + wave * 32 + it * 4 + sub;
    uint4 v = *(const uint4*)(Gb + (size_t)cell * 64 + le * 4);
    float pp = expf(sr[cell] - m);
    a[0] += blo(v.x) * pp; a[1] += bhi(v.x) * pp;
    a[2] += blo(v.y) * pp; a[3] += bhi(v.y) * pp;
    a[4] += blo(v.z) * pp; a[5] += bhi(v.z) * pp;
    a[6] += blo(v.w) * pp; a[7] += bhi(v.w) * pp;
  }
#pragma unroll
  for (int j = 0; j < 8; ++j) {
    a[j] += __shfl_xor(a[j], 16, 64);
    a[j] += __shfl_xor(a[j], 32, 64);
  }
  if (lane < 16) {
#pragma unroll
    for (int j = 0; j < 8; ++j) acc[wave][lane * 8 + j] = a[j];
  }
  __syncthreads();
  if (tid < EDIM) {
    float d = (acc[0][tid] + acc[1][tid] + acc[2][tid] + acc[3][tid]) * invS;
    dup[((size_t)b * 16 + k) * EDIM + tid] = d;
  }
}

// ---------- hop phase C: u_new = u_in + sum_k dup; logits (or final sigmoid) ----------
// grid = BN*16 blocks. Every block of a batch computes the identical u_new
// (deterministic reduction order); block k==0 persists it if u_out != null.
__global__ void __launch_bounds__(256) k_hopC(const uint32_t* __restrict__ Gt,
                                              const float* __restrict__ dup,
                                              const float* __restrict__ u_in,
                                              float* __restrict__ u_out,
                                              float* __restrict__ row_out,
                                              const int* __restrict__ lengths,
                                              float* __restrict__ out) {
  const int b = blockIdx.x >> 4, k = blockIdx.x & 15;
  const int tid = threadIdx.x, wave = tid >> 6, lane = tid & 63;
  __shared__ float u_l[EDIM];
  if (tid < EDIM) {
    float v = u_in[b * EDIM + tid];
    const float* dp = dup + (size_t)b * 16 * EDIM + tid;
#pragma unroll
    for (int kk = 0; kk < 16; ++kk) v += dp[kk * EDIM];
    u_l[tid] = v;
    if (u_out != nullptr && k == 0) u_out[b * EDIM + tid] = v;
  }
  __syncthreads();

  const uint32_t* Gb = Gt + (size_t)b * SN * 64;
  int sub = lane >> 4, le = lane & 15;
  const float4* u4 = (const float4*)u_l;
  float4 ua = u4[le * 2], ub = u4[le * 2 + 1];
  int len = (lengths != nullptr) ? lengths[b] : 0;
#pragma unroll
  for (int it = 0; it < 8; ++it) {
    int cell = k * 128 + wave * 32 + it * 4 + sub;
    uint4 v = *(const uint4*)(Gb + (size_t)cell * 64 + le * 4);
    float s = blo(v.x) * ua.x + bhi(v.x) * ua.y + blo(v.y) * ua.z + bhi(v.y) * ua.w
            + blo(v.z) * ub.x + bhi(v.z) * ub.y + blo(v.w) * ub.z + bhi(v.w) * ub.w;
#pragma unroll
    for (int off = 8; off > 0; off >>= 1) s += __shfl_xor(s, off, 64);
    if (le == 0) {
      if (row_out != nullptr) {
        row_out[(size_t)b * SN + cell] = s;
      } else {
        out[134464 + (size_t)b * SN + cell] =
            (cell < len) ? 1.0f / (1.0f + expf(-s)) : 0.0f;
      }
    }
  }
}

extern "C" void kernel_launch(void* const* d_in, const int* in_sizes, int n_in,
                              void* d_out, int out_size, void* d_ws, size_t ws_size,
                              hipStream_t stream) {
  const int *story = nullptr, *lengths = nullptr;
  const float *hidden = nullptr, *C = nullptr, *Wm = nullptr, *Wb = nullptr,
              *W1w = nullptr, *W1b = nullptr, *W3w = nullptr, *W3b = nullptr,
              *W4w = nullptr, *W4b = nullptr;
  for (int i = 0; i < n_in; ++i) {
    switch (in_sizes[i]) {
      case 16 * 2048 * 4:    story   = (const int*)d_in[i]; break;
      case 16:               lengths = (const int*)d_in[i]; break;
      case 16 * 128:         hidden  = (const float*)d_in[i]; break;
      case 4 * 100000 * 128: C       = (const float*)d_in[i]; break;
      case 128 * 128:        Wm      = (const float*)d_in[i]; break;
      case 128:              Wb      = (const float*)d_in[i]; break;
      case 2 * 128:          W1w     = (const float*)d_in[i]; break;
      case 2:                W1b     = (const float*)d_in[i]; break;
      case 4000 * 128:       W3w     = (const float*)d_in[i]; break;
      case 4000:             W3b     = (const float*)d_in[i]; break;
      case 200 * 128:        W4w     = (const float*)d_in[i]; break;
      case 200:              W4b     = (const float*)d_in[i]; break;
      default: break;
    }
  }
  float* out = (float*)d_out;
  float* ws  = (float*)d_ws;
  float* h   = ws + H_OFF;       // h; reused as u1 after k_heads consumes it
  float* u   = ws + U_OFF;       // u0
  float* row = ws + L0_OFF;      // l0, then l1 in place
  float* dup = ws + DUP_OFF;     // 16*16*128 partial du
  float* pbv = ws + PBV_OFF;
  int*   pbi = (int*)(ws + PBI_OFF);
  uint32_t* G = (uint32_t*)(ws + G_OFF);
  const size_t TSZ = (size_t)BN * SN * 64;   // u32 per G table

  uint32_t k0a, k0b, k1a, k1b, k2a, k2b;
  tf2x32(0u, 42u, 0u, 0u, &k0a, &k0b);
  tf2x32(0u, 42u, 0u, 1u, &k1a, &k1b);
  tf2x32(0u, 42u, 0u, 2u, &k2a, &k2b);

  k_h<<<BN, 128, 0, stream>>>(hidden, Wm, Wb, h, u);
  k_heads<<<432, 256, 0, stream>>>(h, W1w, W1b, W3w, W3b, W4w, W4b,
                                   out, pbv, pbi, k0a, k0b, k1a, k1b, k2a, k2b);
  k_onehot<<<263, 256, 0, stream>>>(pbv, pbi, out);
  k_gather_l0<<<3 * BN * SN / 4, 256, 0, stream>>>(story, C, u, G, row);

  // hop 0: softmax(l0) -> du partials over G[0]=C[1]; u1 = u0 + du; l1 = G[0]·u1
  k_hopB<<<BN * 16, 256, 0, stream>>>(G, row, dup);
  k_hopC<<<BN * 16, 256, 0, stream>>>(G, dup, u, /*u_out=*/h, /*row_out=*/row,
                                      nullptr, out);
  // hop 1: softmax(l1) -> du partials over G[1]=C[2]; u2 = u1 + du;
  //        final logits G[1]·u2 -> masked sigmoid into out
  k_hopB<<<BN * 16, 256, 0, stream>>>(G + TSZ, row, dup);
  k_hopC<<<BN * 16, 256, 0, stream>>>(G + TSZ, dup, /*u_in=*/h, nullptr, nullptr,
                                      lengths, out);
}